// Round 6
// baseline (295.468 us; speedup 1.0000x reference)
//
#include <hip/hip_runtime.h>
#include <hip/hip_fp16.h>

#define HH 1024
#define WW 1024
#define NN 12
#define HWSZ (HH * WW)

// ===== DIAGNOSTIC ROUND (resubmit; R5 failed on container acquire, not kernel) =====
// REP-1 decoy passes + 1 real pass in warp_tile. Purpose: push warp_tile's
// dispatch duration above the ~127us harness poison fills so its counter row
// (FETCH/WRITE/VALUBusy/Occupancy/VGPR) surfaces in the top-5 table.
// Decoy loads use asm-opaqued addresses (no CSE), decoy results feed asm sinks
// (no DCE, rule #17). Only the last pass stores -> outputs bit-identical.
#define REP 6

typedef float  floatx2 __attribute__((ext_vector_type(2)));
typedef unsigned int u32x4 __attribute__((ext_vector_type(4)));

// 16B of texel data (2 adjacent 8B fp16 texels), only 8B-aligned.
struct __attribute__((packed, aligned(8))) pair16 { u32x4 v; };

__device__ __forceinline__ float2 h2f(unsigned int u) {
    __half2 h = *(__half2*)&u;
    return __half22float2(h);
}

__device__ __forceinline__ float sload(float v) {
    int i = __builtin_amdgcn_readfirstlane(__float_as_int(v));
    return __int_as_float(i);
}

// ---------- prepass: planar fp32 (3,H,W) -> packed (H,W) half4 {rg, b0} ----------
__global__ __launch_bounds__(256) void pack_kernel(const float* __restrict__ x,
                                                   uint2* __restrict__ xp) {
    int i = (blockIdx.x * 256 + threadIdx.x) * 4;
    float4 r = *(const float4*)(x + i);
    float4 g = *(const float4*)(x + i + HWSZ);
    float4 b = *(const float4*)(x + i + 2 * HWSZ);

    __half2 rg0 = __float22half2_rn(make_float2(r.x, g.x));
    __half2 rg1 = __float22half2_rn(make_float2(r.y, g.y));
    __half2 rg2 = __float22half2_rn(make_float2(r.z, g.z));
    __half2 rg3 = __float22half2_rn(make_float2(r.w, g.w));
    __half2 b0  = __float22half2_rn(make_float2(b.x, 0.f));
    __half2 b1  = __float22half2_rn(make_float2(b.y, 0.f));
    __half2 b2  = __float22half2_rn(make_float2(b.z, 0.f));
    __half2 b3  = __float22half2_rn(make_float2(b.w, 0.f));

    u32x4 v0 = { *(unsigned*)&rg0, *(unsigned*)&b0, *(unsigned*)&rg1, *(unsigned*)&b1 };
    u32x4 v1 = { *(unsigned*)&rg2, *(unsigned*)&b2, *(unsigned*)&rg3, *(unsigned*)&b3 };
    u32x4* dst = (u32x4*)(xp + i);
    dst[0] = v0;
    dst[1] = v1;
}

// ---------- main: R4 structure (2 px/thread, 8 waves/SIMD) x REP passes ----------
__global__ __launch_bounds__(256, 8) void warp_tile_kernel(
    const uint2* __restrict__ xp,     // (H, W) half4 texels
    const float* __restrict__ theta,  // (12, 2, 3)
    float* __restrict__ xs,           // (12, 3, H, W)
    float* __restrict__ os)           // (12, H, W)
{
    int wl = threadIdx.x & 15;        // 16 w-groups -> 32 px wide per wave row
    int hl = threadIdx.x >> 4;        // 16 rows per block (4 rows per wave)
    int w2 = (blockIdx.x * 16 + wl) * 2;
    int h  = blockIdx.y * 16 + hl;
    int m  = blockIdx.z;

    const float* t = theta + m * 6;   // block-uniform
    float t00 = sload(t[0]), t01 = sload(t[1]), t02 = sload(t[2]);
    float t10 = sload(t[3]), t11 = sload(t[4]), t12 = sload(t[5]);

    float gx0 = (w2 + 0.5f) * (2.0f / WW) - 1.0f;
    float gy  = (h  + 0.5f) * (2.0f / HH) - 1.0f;
    float ix0 = ((t00 * gx0 + t01 * gy + t02 + 1.0f) * WW - 1.0f) * 0.5f;
    float iy0 = ((t10 * gx0 + t11 * gy + t12 + 1.0f) * HH - 1.0f) * 0.5f;

    // ---- addressing (computed once, shared by all passes) ----
    int   idx0a[2], idx1a[2];
    float fxa[2], fya[2];
    int   x0a[2], y0a[2];

    #pragma unroll
    for (int j = 0; j < 2; ++j) {
        float ix = ix0 + (float)j * t00;
        float iy = iy0 + (float)j * t10;

        float xf = floorf(ix), yf = floorf(iy);
        int x0 = (int)xf, y0 = (int)yf;

        int bx  = min(max(x0, 0), WW - 2);       // pair base column
        int by0 = min(max(y0, 0), HH - 1);
        int by1 = min(max(y0 + 1, 0), HH - 1);

        idx0a[j] = by0 * WW + bx;
        idx1a[j] = by1 * WW + bx;
        fxa[j] = ix - xf;
        fya[j] = iy - yf;
        x0a[j] = x0;
        y0a[j] = y0;
    }

    // ---- REP passes: load + blend; only the last pass stores ----
    #pragma unroll 1
    for (int rep = 0; rep < REP; ++rep) {
        u32x4 P0[2], P1[2];
        #pragma unroll
        for (int j = 0; j < 2; ++j) {
            int i0 = idx0a[j], i1 = idx1a[j];
            // opaque the addresses so the compiler cannot CSE loads across passes
            asm volatile("" : "+v"(i0), "+v"(i1));
            P0[j] = ((const pair16*)(xp + i0))->v;
            P1[j] = ((const pair16*)(xp + i1))->v;
        }

        float r0[2], r1[2], r2[2], ro[2];
        #pragma unroll
        for (int j = 0; j < 2; ++j) {
            int x0 = x0a[j], y0 = y0a[j];
            float fx = fxa[j], fy = fya[j];

            bool vx0 = (unsigned)x0 < WW;
            bool vx1 = (unsigned)(x0 + 1) < WW;
            bool vy0 = (unsigned)y0 < HH;
            bool vy1 = (unsigned)(y0 + 1) < HH;

            float ax0 = vx0 ? (1.0f - fx) : 0.0f;
            float ax1 = vx1 ? fx          : 0.0f;
            float ay0 = vy0 ? (1.0f - fy) : 0.0f;
            float ay1 = vy1 ? fy          : 0.0f;

            float w00 = ax0 * ay0, w10 = ax1 * ay0;
            float w01 = ax0 * ay1, w11 = ax1 * ay1;

            bool lo0 = (x0 < WW - 1);
            bool lo1 = (x0 < 0);

            u32x4 p0 = P0[j], p1 = P1[j];
            unsigned rg00 = lo0 ? p0.x : p0.z,  bb00 = lo0 ? p0.y : p0.w;
            unsigned rg10 = lo1 ? p0.x : p0.z,  bb10 = lo1 ? p0.y : p0.w;
            unsigned rg01 = lo0 ? p1.x : p1.z,  bb01 = lo0 ? p1.y : p1.w;
            unsigned rg11 = lo1 ? p1.x : p1.z,  bb11 = lo1 ? p1.y : p1.w;

            float2 c00 = h2f(rg00), c10 = h2f(rg10), c01 = h2f(rg01), c11 = h2f(rg11);
            float  b00 = h2f(bb00).x, b10 = h2f(bb10).x, b01 = h2f(bb01).x, b11 = h2f(bb11).x;

            r0[j] = fmaf(w00, c00.x, fmaf(w10, c10.x, fmaf(w01, c01.x, w11 * c11.x)));
            r1[j] = fmaf(w00, c00.y, fmaf(w10, c10.y, fmaf(w01, c01.y, w11 * c11.y)));
            r2[j] = fmaf(w00, b00,   fmaf(w10, b10,   fmaf(w01, b01,   w11 * b11)));
            ro[j] = (ax0 + ax1) * (ay0 + ay1);
        }

        if (rep == REP - 1) {
            int pix = h * WW + w2;
            floatx2* o0 = (floatx2*)(xs + ((size_t)(m * 3 + 0)) * HWSZ + pix);
            floatx2* o1 = (floatx2*)(xs + ((size_t)(m * 3 + 1)) * HWSZ + pix);
            floatx2* o2 = (floatx2*)(xs + ((size_t)(m * 3 + 2)) * HWSZ + pix);
            floatx2* oo = (floatx2*)(os + (size_t)m * HWSZ + pix);
            floatx2 s0 = {r0[0], r0[1]};
            floatx2 s1 = {r1[0], r1[1]};
            floatx2 s2 = {r2[0], r2[1]};
            floatx2 so = {ro[0], ro[1]};
            __builtin_nontemporal_store(s0, o0);
            __builtin_nontemporal_store(s1, o1);
            __builtin_nontemporal_store(s2, o2);
            __builtin_nontemporal_store(so, oo);
        } else {
            // keep decoy results live (rule #17: DCE-proof ablation)
            asm volatile("" :: "v"(r0[0]), "v"(r0[1]), "v"(r1[0]), "v"(r1[1]),
                              "v"(r2[0]), "v"(r2[1]), "v"(ro[0]), "v"(ro[1]));
        }
    }
}

// ---------- fallback (R1 kernel) if ws too small ----------
__global__ __launch_bounds__(256) void warp_kernel(
    const float* __restrict__ x, const float* __restrict__ theta,
    float* __restrict__ xs, float* __restrict__ os)
{
    int idx = blockIdx.x * blockDim.x + threadIdx.x;
    if (idx >= NN * HWSZ) return;
    int m = idx >> 20;
    int h = (idx >> 10) & (HH - 1);
    int w = idx & (WW - 1);
    const float* t = theta + m * 6;
    float t00 = t[0], t01 = t[1], t02 = t[2];
    float t10 = t[3], t11 = t[4], t12 = t[5];
    float gx = (w + 0.5f) * (2.0f / WW) - 1.0f;
    float gy = (h + 0.5f) * (2.0f / HH) - 1.0f;
    float u = t00 * gx + t01 * gy + t02;
    float v = t10 * gx + t11 * gy + t12;
    float ix = ((u + 1.0f) * WW - 1.0f) * 0.5f;
    float iy = ((v + 1.0f) * HH - 1.0f) * 0.5f;
    float x0f = floorf(ix), y0f = floorf(iy);
    int x0 = (int)x0f, y0 = (int)y0f;
    int x1 = x0 + 1, y1 = y0 + 1;
    float fx = ix - x0f, fy = iy - y0f;
    float wx0 = 1.0f - fx, wx1 = fx, wy0 = 1.0f - fy, wy1 = fy;
    bool vx0 = (x0 >= 0) & (x0 < WW), vx1 = (x1 >= 0) & (x1 < WW);
    bool vy0 = (y0 >= 0) & (y0 < HH), vy1 = (y1 >= 0) & (y1 < HH);
    int cx0 = min(max(x0, 0), WW - 1), cx1 = min(max(x1, 0), WW - 1);
    int cy0 = min(max(y0, 0), HH - 1), cy1 = min(max(y1, 0), HH - 1);
    float w00 = wx0 * wy0 * ((vx0 & vy0) ? 1.0f : 0.0f);
    float w10 = wx1 * wy0 * ((vx1 & vy0) ? 1.0f : 0.0f);
    float w01 = wx0 * wy1 * ((vx0 & vy1) ? 1.0f : 0.0f);
    float w11 = wx1 * wy1 * ((vx1 & vy1) ? 1.0f : 0.0f);
    int i00 = cy0 * WW + cx0, i10 = cy0 * WW + cx1;
    int i01 = cy1 * WW + cx0, i11 = cy1 * WW + cx1;
    int pix = h * WW + w;
    #pragma unroll
    for (int c = 0; c < 3; ++c) {
        const float* p = x + c * HWSZ;
        float val = w00 * p[i00] + w10 * p[i10] + w01 * p[i01] + w11 * p[i11];
        xs[(m * 3 + c) * HWSZ + pix] = val;
    }
    os[m * HWSZ + pix] = w00 + w10 + w01 + w11;
}

__global__ void tail_kernel(const float* __restrict__ theta,
                            float* __restrict__ zout,
                            float* __restrict__ izout)
{
    int m = threadIdx.x;
    if (m >= NN) return;
    const float* t = theta + m * 6;
    float a = t[0], b = t[1], tx = t[2];
    float c = t[3], d = t[4], ty = t[5];
    #pragma unroll
    for (int i = 0; i < 6; ++i) zout[m * 6 + i] = t[i];
    float det = a * d - b * c;
    float id = 1.0f / det;
    float ia = d * id, ib = -b * id, ic = -c * id, idd = a * id;
    float itx = -(ia * tx + ib * ty);
    float ity = -(ic * tx + idd * ty);
    izout[m * 6 + 0] = ia;  izout[m * 6 + 1] = ib;  izout[m * 6 + 2] = itx;
    izout[m * 6 + 3] = ic;  izout[m * 6 + 4] = idd; izout[m * 6 + 5] = ity;
}

extern "C" void kernel_launch(void* const* d_in, const int* in_sizes, int n_in,
                              void* d_out, int out_size, void* d_ws, size_t ws_size,
                              hipStream_t stream) {
    const float* x     = (const float*)d_in[0];   // (1,3,1024,1024)
    const float* theta = (const float*)d_in[1];   // (1,12,2,3)

    float* out = (float*)d_out;
    float* xs  = out;
    float* os  = xs + (size_t)NN * 3 * HWSZ;
    float* z   = os + (size_t)NN * HWSZ;
    float* iz  = z + NN * 6;

    if (ws_size >= (size_t)HWSZ * sizeof(uint2)) {
        uint2* xp = (uint2*)d_ws;
        pack_kernel<<<HWSZ / 4 / 256, 256, 0, stream>>>(x, xp);
        dim3 grid(WW / 32, HH / 16, NN);
        warp_tile_kernel<<<grid, 256, 0, stream>>>(xp, theta, xs, os);
    } else {
        int total = NN * HWSZ;
        warp_kernel<<<(total + 255) / 256, 256, 0, stream>>>(x, theta, xs, os);
    }
    tail_kernel<<<1, 64, 0, stream>>>(theta, z, iz);
}

// Round 7
// 216.213 us; speedup vs baseline: 1.3666x; 1.3666x over previous
//
#include <hip/hip_runtime.h>
#include <hip/hip_fp16.h>

#define HH 1024
#define WW 1024
#define NN 12
#define HWSZ (HH * WW)

typedef float  floatx2 __attribute__((ext_vector_type(2)));
typedef unsigned int u32x4 __attribute__((ext_vector_type(4)));

// 16B of texel data (2 adjacent 8B fp16 texels), only 8B-aligned.
struct __attribute__((packed, aligned(8))) pair16 { u32x4 v; };

__device__ __forceinline__ float2 h2f(unsigned int u) {
    __half2 h = *(__half2*)&u;
    return __half22float2(h);
}

__device__ __forceinline__ float sload(float v) {
    int i = __builtin_amdgcn_readfirstlane(__float_as_int(v));
    return __int_as_float(i);
}

// ---------- prepass: pack planar fp32 -> half4 texels, + fused tail (z/iz) ----------
__global__ __launch_bounds__(256) void pack_tail_kernel(const float* __restrict__ x,
                                                        uint2* __restrict__ xp,
                                                        const float* __restrict__ theta,
                                                        float* __restrict__ zout,
                                                        float* __restrict__ izout) {
    int i = (blockIdx.x * 256 + threadIdx.x) * 4;
    float4 r = *(const float4*)(x + i);
    float4 g = *(const float4*)(x + i + HWSZ);
    float4 b = *(const float4*)(x + i + 2 * HWSZ);

    __half2 rg0 = __float22half2_rn(make_float2(r.x, g.x));
    __half2 rg1 = __float22half2_rn(make_float2(r.y, g.y));
    __half2 rg2 = __float22half2_rn(make_float2(r.z, g.z));
    __half2 rg3 = __float22half2_rn(make_float2(r.w, g.w));
    __half2 b0  = __float22half2_rn(make_float2(b.x, 0.f));
    __half2 b1  = __float22half2_rn(make_float2(b.y, 0.f));
    __half2 b2  = __float22half2_rn(make_float2(b.z, 0.f));
    __half2 b3  = __float22half2_rn(make_float2(b.w, 0.f));

    u32x4 v0 = { *(unsigned*)&rg0, *(unsigned*)&b0, *(unsigned*)&rg1, *(unsigned*)&b1 };
    u32x4 v1 = { *(unsigned*)&rg2, *(unsigned*)&b2, *(unsigned*)&rg3, *(unsigned*)&b3 };
    u32x4* dst = (u32x4*)(xp + i);
    dst[0] = v0;
    dst[1] = v1;

    // fused tail: one launch fewer (saves an inter-kernel gap)
    if (blockIdx.x == 0 && threadIdx.x < NN) {
        int m = threadIdx.x;
        const float* t = theta + m * 6;
        float a = t[0], bb = t[1], tx = t[2];
        float c = t[3], d  = t[4], ty = t[5];
        #pragma unroll
        for (int k = 0; k < 6; ++k) zout[m * 6 + k] = t[k];
        float det = a * d - bb * c;
        float id = 1.0f / det;
        float ia = d * id, ib = -bb * id, ic = -c * id, idd = a * id;
        float itx = -(ia * tx + ib * ty);
        float ity = -(ic * tx + idd * ty);
        izout[m * 6 + 0] = ia;  izout[m * 6 + 1] = ib;  izout[m * 6 + 2] = itx;
        izout[m * 6 + 3] = ic;  izout[m * 6 + 4] = idd; izout[m * 6 + 5] = ity;
    }
}

// ---------- main: 2 px/thread, 8 waves/SIMD, block-uniform interior fast path ----------
// R6 counters: VGPR=28, loads cache-resident (FETCH ~0), VALUBusy 60% on load+blend
// passes -> kernel is VALU/issue-limited over a 33us store floor. Interior blocks
// (source bbox fully inside the image, tested block-uniformly from the 4 affine
// corners with 0.5px margin) skip ALL masks/clamps/pair-selects: ~40% VALU cut.
// Border blocks keep the verified full path.
__global__ __launch_bounds__(256, 8) void warp_tile_kernel(
    const uint2* __restrict__ xp,     // (H, W) half4 texels
    const float* __restrict__ theta,  // (12, 2, 3)
    float* __restrict__ xs,           // (12, 3, H, W)
    float* __restrict__ os)           // (12, H, W)
{
    int wl = threadIdx.x & 15;        // 16 w-groups -> 32 px wide per block
    int hl = threadIdx.x >> 4;        // 16 rows per block
    int w2 = (blockIdx.x * 16 + wl) * 2;
    int h  = blockIdx.y * 16 + hl;
    int m  = blockIdx.z;

    const float* t = theta + m * 6;   // block-uniform
    float t00 = sload(t[0]), t01 = sload(t[1]), t02 = sload(t[2]);
    float t10 = sload(t[3]), t11 = sload(t[4]), t12 = sload(t[5]);

    float gx0 = (w2 + 0.5f) * (2.0f / WW) - 1.0f;
    float gy  = (h  + 0.5f) * (2.0f / HH) - 1.0f;
    float ix0 = ((t00 * gx0 + t01 * gy + t02 + 1.0f) * WW - 1.0f) * 0.5f;
    float iy0 = ((t10 * gx0 + t11 * gy + t12 + 1.0f) * HH - 1.0f) * 0.5f;
    // per-pixel step: d(ix)/d(w)=t00, d(iy)/d(w)=t10

    // ---- block-uniform interior test (affine => extrema at the 4 tile corners) ----
    float cwa = (blockIdx.x * 32 + 0.5f)  * (2.0f / WW) - 1.0f;
    float cwb = (blockIdx.x * 32 + 31.5f) * (2.0f / WW) - 1.0f;
    float cha = (blockIdx.y * 16 + 0.5f)  * (2.0f / HH) - 1.0f;
    float chb = (blockIdx.y * 16 + 15.5f) * (2.0f / HH) - 1.0f;

    float ix_aa = ((t00 * cwa + t01 * cha + t02 + 1.0f) * WW - 1.0f) * 0.5f;
    float ix_ba = ((t00 * cwb + t01 * cha + t02 + 1.0f) * WW - 1.0f) * 0.5f;
    float ix_ab = ((t00 * cwa + t01 * chb + t02 + 1.0f) * WW - 1.0f) * 0.5f;
    float ix_bb = ((t00 * cwb + t01 * chb + t02 + 1.0f) * WW - 1.0f) * 0.5f;
    float iy_aa = ((t10 * cwa + t11 * cha + t12 + 1.0f) * HH - 1.0f) * 0.5f;
    float iy_ba = ((t10 * cwb + t11 * cha + t12 + 1.0f) * HH - 1.0f) * 0.5f;
    float iy_ab = ((t10 * cwa + t11 * chb + t12 + 1.0f) * HH - 1.0f) * 0.5f;
    float iy_bb = ((t10 * cwb + t11 * chb + t12 + 1.0f) * HH - 1.0f) * 0.5f;

    float ixmin = fminf(fminf(ix_aa, ix_ba), fminf(ix_ab, ix_bb));
    float ixmax = fmaxf(fmaxf(ix_aa, ix_ba), fmaxf(ix_ab, ix_bb));
    float iymin = fminf(fminf(iy_aa, iy_ba), fminf(iy_ab, iy_bb));
    float iymax = fmaxf(fmaxf(iy_aa, iy_ba), fmaxf(iy_ab, iy_bb));

    // 0.5px margin >> fp rounding; guarantees x0>=0, x0+1<=WW-1, y0>=0, y0+1<=HH-1
    bool interior = (ixmin > 0.5f) & (ixmax < (float)(WW) - 1.5f) &
                    (iymin > 0.5f) & (iymax < (float)(HH) - 1.5f);

    float r0[2], r1[2], r2[2], ro[2];

    if (interior) {
        // ---- fast path: no masks, no clamps, no pair-select ----
        u32x4 P0[2], P1[2];
        float fxa[2], fya[2];
        #pragma unroll
        for (int j = 0; j < 2; ++j) {
            float ix = ix0 + (float)j * t00;
            float iy = iy0 + (float)j * t10;
            float xf = floorf(ix), yf = floorf(iy);
            int base = (int)yf * WW + (int)xf;
            P0[j] = ((const pair16*)(xp + base))->v;        // texels x0,x0+1 row y0
            P1[j] = ((const pair16*)(xp + base + WW))->v;   // row y0+1
            fxa[j] = ix - xf;
            fya[j] = iy - yf;
        }
        #pragma unroll
        for (int j = 0; j < 2; ++j) {
            float fx = fxa[j], fy = fya[j];
            float wx0 = 1.0f - fx, wx1 = fx;
            float wy0 = 1.0f - fy, wy1 = fy;
            float w00 = wx0 * wy0, w10 = wx1 * wy0;
            float w01 = wx0 * wy1, w11 = wx1 * wy1;

            u32x4 p0 = P0[j], p1 = P1[j];
            float2 c00 = h2f(p0.x), c10 = h2f(p0.z), c01 = h2f(p1.x), c11 = h2f(p1.z);
            float  b00 = h2f(p0.y).x, b10 = h2f(p0.w).x, b01 = h2f(p1.y).x, b11 = h2f(p1.w).x;

            r0[j] = fmaf(w00, c00.x, fmaf(w10, c10.x, fmaf(w01, c01.x, w11 * c11.x)));
            r1[j] = fmaf(w00, c00.y, fmaf(w10, c10.y, fmaf(w01, c01.y, w11 * c11.y)));
            r2[j] = fmaf(w00, b00,   fmaf(w10, b10,   fmaf(w01, b01,   w11 * b11)));
            ro[j] = 1.0f;   // all corners valid: weights sum to 1 (|diff vs ref| ~1e-7)
        }
    } else {
        // ---- full path (verified R4) ----
        u32x4 P0[2], P1[2];
        float fxa[2], fya[2];
        int   x0a[2], y0a[2];
        #pragma unroll
        for (int j = 0; j < 2; ++j) {
            float ix = ix0 + (float)j * t00;
            float iy = iy0 + (float)j * t10;
            float xf = floorf(ix), yf = floorf(iy);
            int x0 = (int)xf, y0 = (int)yf;
            int bx  = min(max(x0, 0), WW - 2);
            int by0 = min(max(y0, 0), HH - 1);
            int by1 = min(max(y0 + 1, 0), HH - 1);
            P0[j] = ((const pair16*)(xp + by0 * WW + bx))->v;
            P1[j] = ((const pair16*)(xp + by1 * WW + bx))->v;
            fxa[j] = ix - xf;  fya[j] = iy - yf;
            x0a[j] = x0;       y0a[j] = y0;
        }
        #pragma unroll
        for (int j = 0; j < 2; ++j) {
            int x0 = x0a[j], y0 = y0a[j];
            float fx = fxa[j], fy = fya[j];

            bool vx0 = (unsigned)x0 < WW;
            bool vx1 = (unsigned)(x0 + 1) < WW;
            bool vy0 = (unsigned)y0 < HH;
            bool vy1 = (unsigned)(y0 + 1) < HH;

            float ax0 = vx0 ? (1.0f - fx) : 0.0f;
            float ax1 = vx1 ? fx          : 0.0f;
            float ay0 = vy0 ? (1.0f - fy) : 0.0f;
            float ay1 = vy1 ? fy          : 0.0f;

            float w00 = ax0 * ay0, w10 = ax1 * ay0;
            float w01 = ax0 * ay1, w11 = ax1 * ay1;

            bool lo0 = (x0 < WW - 1);
            bool lo1 = (x0 < 0);

            u32x4 p0 = P0[j], p1 = P1[j];
            unsigned rg00 = lo0 ? p0.x : p0.z,  bb00 = lo0 ? p0.y : p0.w;
            unsigned rg10 = lo1 ? p0.x : p0.z,  bb10 = lo1 ? p0.y : p0.w;
            unsigned rg01 = lo0 ? p1.x : p1.z,  bb01 = lo0 ? p1.y : p1.w;
            unsigned rg11 = lo1 ? p1.x : p1.z,  bb11 = lo1 ? p1.y : p1.w;

            float2 c00 = h2f(rg00), c10 = h2f(rg10), c01 = h2f(rg01), c11 = h2f(rg11);
            float  b00 = h2f(bb00).x, b10 = h2f(bb10).x, b01 = h2f(bb01).x, b11 = h2f(bb11).x;

            r0[j] = fmaf(w00, c00.x, fmaf(w10, c10.x, fmaf(w01, c01.x, w11 * c11.x)));
            r1[j] = fmaf(w00, c00.y, fmaf(w10, c10.y, fmaf(w01, c01.y, w11 * c11.y)));
            r2[j] = fmaf(w00, b00,   fmaf(w10, b10,   fmaf(w01, b01,   w11 * b11)));
            ro[j] = (ax0 + ax1) * (ay0 + ay1);
        }
    }

    int pix = h * WW + w2;
    floatx2* o0 = (floatx2*)(xs + ((size_t)(m * 3 + 0)) * HWSZ + pix);
    floatx2* o1 = (floatx2*)(xs + ((size_t)(m * 3 + 1)) * HWSZ + pix);
    floatx2* o2 = (floatx2*)(xs + ((size_t)(m * 3 + 2)) * HWSZ + pix);
    floatx2* oo = (floatx2*)(os + (size_t)m * HWSZ + pix);
    floatx2 s0 = {r0[0], r0[1]};
    floatx2 s1 = {r1[0], r1[1]};
    floatx2 s2 = {r2[0], r2[1]};
    floatx2 so = {ro[0], ro[1]};
    __builtin_nontemporal_store(s0, o0);
    __builtin_nontemporal_store(s1, o1);
    __builtin_nontemporal_store(s2, o2);
    __builtin_nontemporal_store(so, oo);
}

// ---------- fallback if ws too small ----------
__global__ __launch_bounds__(256) void warp_kernel(
    const float* __restrict__ x, const float* __restrict__ theta,
    float* __restrict__ xs, float* __restrict__ os)
{
    int idx = blockIdx.x * blockDim.x + threadIdx.x;
    if (idx >= NN * HWSZ) return;
    int m = idx >> 20;
    int h = (idx >> 10) & (HH - 1);
    int w = idx & (WW - 1);
    const float* t = theta + m * 6;
    float t00 = t[0], t01 = t[1], t02 = t[2];
    float t10 = t[3], t11 = t[4], t12 = t[5];
    float gx = (w + 0.5f) * (2.0f / WW) - 1.0f;
    float gy = (h + 0.5f) * (2.0f / HH) - 1.0f;
    float u = t00 * gx + t01 * gy + t02;
    float v = t10 * gx + t11 * gy + t12;
    float ix = ((u + 1.0f) * WW - 1.0f) * 0.5f;
    float iy = ((v + 1.0f) * HH - 1.0f) * 0.5f;
    float x0f = floorf(ix), y0f = floorf(iy);
    int x0 = (int)x0f, y0 = (int)y0f;
    int x1 = x0 + 1, y1 = y0 + 1;
    float fx = ix - x0f, fy = iy - y0f;
    float wx0 = 1.0f - fx, wx1 = fx, wy0 = 1.0f - fy, wy1 = fy;
    bool vx0 = (x0 >= 0) & (x0 < WW), vx1 = (x1 >= 0) & (x1 < WW);
    bool vy0 = (y0 >= 0) & (y0 < HH), vy1 = (y1 >= 0) & (y1 < HH);
    int cx0 = min(max(x0, 0), WW - 1), cx1 = min(max(x1, 0), WW - 1);
    int cy0 = min(max(y0, 0), HH - 1), cy1 = min(max(y1, 0), HH - 1);
    float w00 = wx0 * wy0 * ((vx0 & vy0) ? 1.0f : 0.0f);
    float w10 = wx1 * wy0 * ((vx1 & vy0) ? 1.0f : 0.0f);
    float w01 = wx0 * wy1 * ((vx0 & vy1) ? 1.0f : 0.0f);
    float w11 = wx1 * wy1 * ((vx1 & vy1) ? 1.0f : 0.0f);
    int i00 = cy0 * WW + cx0, i10 = cy0 * WW + cx1;
    int i01 = cy1 * WW + cx0, i11 = cy1 * WW + cx1;
    int pix = h * WW + w;
    #pragma unroll
    for (int c = 0; c < 3; ++c) {
        const float* p = x + c * HWSZ;
        float val = w00 * p[i00] + w10 * p[i10] + w01 * p[i01] + w11 * p[i11];
        xs[(m * 3 + c) * HWSZ + pix] = val;
    }
    os[m * HWSZ + pix] = w00 + w10 + w01 + w11;
}

__global__ void tail_kernel(const float* __restrict__ theta,
                            float* __restrict__ zout,
                            float* __restrict__ izout)
{
    int m = threadIdx.x;
    if (m >= NN) return;
    const float* t = theta + m * 6;
    float a = t[0], b = t[1], tx = t[2];
    float c = t[3], d = t[4], ty = t[5];
    #pragma unroll
    for (int i = 0; i < 6; ++i) zout[m * 6 + i] = t[i];
    float det = a * d - b * c;
    float id = 1.0f / det;
    float ia = d * id, ib = -b * id, ic = -c * id, idd = a * id;
    float itx = -(ia * tx + ib * ty);
    float ity = -(ic * tx + idd * ty);
    izout[m * 6 + 0] = ia;  izout[m * 6 + 1] = ib;  izout[m * 6 + 2] = itx;
    izout[m * 6 + 3] = ic;  izout[m * 6 + 4] = idd; izout[m * 6 + 5] = ity;
}

extern "C" void kernel_launch(void* const* d_in, const int* in_sizes, int n_in,
                              void* d_out, int out_size, void* d_ws, size_t ws_size,
                              hipStream_t stream) {
    const float* x     = (const float*)d_in[0];   // (1,3,1024,1024)
    const float* theta = (const float*)d_in[1];   // (1,12,2,3)

    float* out = (float*)d_out;
    float* xs  = out;
    float* os  = xs + (size_t)NN * 3 * HWSZ;
    float* z   = os + (size_t)NN * HWSZ;
    float* iz  = z + NN * 6;

    if (ws_size >= (size_t)HWSZ * sizeof(uint2)) {
        uint2* xp = (uint2*)d_ws;
        pack_tail_kernel<<<HWSZ / 4 / 256, 256, 0, stream>>>(x, xp, theta, z, iz);
        dim3 grid(WW / 32, HH / 16, NN);
        warp_tile_kernel<<<grid, 256, 0, stream>>>(xp, theta, xs, os);
    } else {
        int total = NN * HWSZ;
        warp_kernel<<<(total + 255) / 256, 256, 0, stream>>>(x, theta, xs, os);
        tail_kernel<<<1, 64, 0, stream>>>(theta, z, iz);
    }
}